// Round 6
// baseline (146.569 us; speedup 1.0000x reference)
//
#include <hip/hip_runtime.h>

// Legendre2 via split-precision MFMA, v6: two-tier B-operand storage.
// Prep kernel materializes f16 hi/lo fragment tables of A (=coef*Tnorm) and
// bf16 hi/lo fragment table of C into d_ws in final MFMA lane layout.
// Main kernel (512 thr, 8 waves): hi-frags + C staged in LDS (73.7 KB total
// -> 2 blocks/CU = 4 waves/SIMD with clean 512-thread codegen), lo-frags
// read straight from global (48 KB, L2-resident, shared by all blocks).
// W_i = Z @ A_i^T as f16 hi/lo 3-term MFMA (f32 accum), elementwise Legendre
// fold in f32 regs, epilogue P6 @ C^T + beta as bf16 hi/lo 3-term MFMA.
// N=524288, D=64, K=64, O=32, DEGREE=6.

typedef _Float16 f16x8 __attribute__((ext_vector_type(8)));
typedef short    s16x8 __attribute__((ext_vector_type(8)));
typedef float    f32x4 __attribute__((ext_vector_type(4)));

#define NN      524288
#define BLOCKS  512
#define THREADS 512
#define NWAVES  8
#define ROWS_PER_WAVE 128               // 512 blocks * 8 waves * 128 = N
#define NITER   4                       // 4 x 32 rows per wave

// d_ws byte layout (prep kernel output): BH and CF contiguous so the main
// kernel's LDS fill is one linear copy.
#define WS_BH   0                       // 48 frags * 1 KB  (f16 hi of A)
#define WS_CF   49152                   // 8 frags * 1 KB   (bf16 h/l of C)
#define WS_BL   57344                   // 48 frags * 1 KB  (f16 lo of A)
#define WS_TOTAL 106496

// main-kernel LDS byte offsets
#define BH_OFF  0                       // 48 KB
#define CF_OFF  49152                   // 8 KB
#define SCR_OFF 57344                   // 8 waves * 2 KB transpose scratch
#define SMEM_BYTES (SCR_OFF + NWAVES * 2048)   // 73728 B -> 2 blocks/CU

__device__ __forceinline__ unsigned short f2bf(float x) {
    unsigned u = __builtin_bit_cast(unsigned, x);
    return (unsigned short)((u + 0x7FFFu + ((u >> 16) & 1u)) >> 16);
}

// ---------------------------------------------------------------------------
// prep: build fragment tables in d_ws (runs every launch; ~100 KB of work)
// ---------------------------------------------------------------------------
__global__ __launch_bounds__(512) void leg_prep(
    const float* __restrict__ T, const float* __restrict__ Cm,
    char* __restrict__ ws)
{
    __shared__ float scale_s[384];
    const int tid = (int)threadIdx.x;

    // per-row scales: mat==0 -> 1, else coef/rowsum
    if (tid < 384) {
        const int mat = tid >> 6, kc = tid & 63;
        const float4* tr = (const float4*)(T + (size_t)((mat << 6) + kc) * 64);
        float s = 0.f;
        #pragma unroll
        for (int q = 0; q < 16; ++q) { float4 v = tr[q]; s += v.x + v.y + v.z + v.w; }
        float sc;
        if (mat == 0) sc = 1.f;
        else { const float fi = (float)(mat + 1); sc = (2.f * fi - 1.f) / fi / s; }
        scale_s[tid] = sc;
    }
    __syncthreads();

    // A fragments: frag(mat,s,f), lane l supplies A[col][32s+(l>>4)*8+j]*scale
    // with col=(l&15)+16f.  3072 items -> hi table + lo table.
    for (int g = tid; g < 3072; g += 512) {
        const int mat = g >> 9;
        const int s   = (g >> 8) & 1;
        const int f   = (g >> 6) & 3;
        const int l   = g & 63;
        const int kc  = (l & 15) + (f << 4);
        const int d0  = ((l >> 4) << 3) + (s << 5);
        const float sc = scale_s[(mat << 6) + kc];
        const float* src = T + (size_t)((mat << 6) + kc) * 64 + d0;
        const float4 v0 = *(const float4*)(src);
        const float4 v1 = *(const float4*)(src + 4);
        const float vv[8] = {v0.x, v0.y, v0.z, v0.w, v1.x, v1.y, v1.z, v1.w};
        f16x8 hi, lo;
        #pragma unroll
        for (int j = 0; j < 8; ++j) {
            const float x = vv[j] * sc;
            const _Float16 h = (_Float16)x;
            hi[j] = h;
            lo[j] = (_Float16)(x - (float)h);
        }
        const int fr = (((mat << 1) + s) << 2) + f;
        *(f16x8*)(ws + WS_BH + fr * 1024 + l * 16) = hi;
        *(f16x8*)(ws + WS_BL + fr * 1024 + l * 16) = lo;
    }

    // C fragments (bf16 hi/lo): frag(hl,s,fo), lane l supplies
    // C2[k=32s+(l>>4)*8+j][o=(l&15)+16fo] = C[o][k].  512 items.
    {
        const int hl = (tid >> 8) & 1;
        const int s  = (tid >> 7) & 1;
        const int fo = (tid >> 6) & 1;
        const int l  = tid & 63;
        const int o  = (l & 15) + (fo << 4);
        const int k0 = ((l >> 4) << 3) + (s << 5);
        const float* src = Cm + (size_t)o * 64 + k0;
        const float4 v0 = *(const float4*)src;
        const float4 v1 = *(const float4*)(src + 4);
        const float vv[8] = {v0.x, v0.y, v0.z, v0.w, v1.x, v1.y, v1.z, v1.w};
        s16x8 fr;
        #pragma unroll
        for (int j = 0; j < 8; ++j) {
            const float x = vv[j];
            const unsigned short h = f2bf(x);
            if (hl) {
                const float hf = __builtin_bit_cast(float, (unsigned)h << 16);
                fr[j] = (short)f2bf(x - hf);
            } else {
                fr[j] = (short)h;
            }
        }
        *(s16x8*)(ws + WS_CF + ((((hl << 1) + s) << 1) + fo) * 1024 + l * 16) = fr;
    }
}

// ---------------------------------------------------------------------------
// main
// ---------------------------------------------------------------------------
__global__ __launch_bounds__(THREADS) void leg_mfma(
    const float* __restrict__ z, const char* __restrict__ ws,
    const float* __restrict__ beta, float* __restrict__ out)
{
    extern __shared__ char smem[];
    const int tid  = (int)threadIdx.x;
    const int lane = tid & 63;
    const int wv   = tid >> 6;
    const int lrow = lane & 15;          // row (A-op) / col (C/D) index
    const int lhi  = lane >> 4;          // 0..3

    // stage BH + CF into LDS: one linear 56 KB copy (ws layout matches LDS)
    for (int i = tid; i < (48 * 1024 + 8 * 1024) / 16; i += THREADS) {
        *(f16x8*)(smem + i * 16) = *(const f16x8*)(ws + i * 16);
    }
    __syncthreads();

    const char* wsbl = ws + WS_BL;       // lo-frags stay in global (L2-hot)

    const int    gw      = blockIdx.x * NWAVES + wv;
    const size_t rowbase = (size_t)gw * ROWS_PER_WAVE;
    float* scr = (float*)(smem + SCR_OFF) + wv * 512;   // 16 rows x 32 f32

    const float beta0 = beta[lrow];
    const float beta1 = beta[16 + lrow];

    f16x8 zh[2][2], zl[2][2];

    // one Legendre level: PT := W_mat * PC - b * PT, W folded per-fragment
    auto leg_step = [&](int mat, float b, f32x4 (&PC)[2][4], f32x4 (&PT)[2][4]) {
        #pragma unroll
        for (int f = 0; f < 4; ++f) {
            const int fr0 = mat * 8 + f;       // s=0
            const int fr1 = mat * 8 + 4 + f;   // s=1
            const f16x8 bh0 = *(const f16x8*)(smem + BH_OFF + fr0 * 1024 + lane * 16);
            const f16x8 bh1 = *(const f16x8*)(smem + BH_OFF + fr1 * 1024 + lane * 16);
            const f16x8 bl0 = *(const f16x8*)(wsbl + fr0 * 1024 + lane * 16);
            const f16x8 bl1 = *(const f16x8*)(wsbl + fr1 * 1024 + lane * 16);
            #pragma unroll
            for (int t = 0; t < 2; ++t) {
                f32x4 a = {0.f, 0.f, 0.f, 0.f};
                a = __builtin_amdgcn_mfma_f32_16x16x32_f16(zh[t][0], bh0, a, 0, 0, 0);
                a = __builtin_amdgcn_mfma_f32_16x16x32_f16(zl[t][0], bh0, a, 0, 0, 0);
                a = __builtin_amdgcn_mfma_f32_16x16x32_f16(zh[t][0], bl0, a, 0, 0, 0);
                a = __builtin_amdgcn_mfma_f32_16x16x32_f16(zh[t][1], bh1, a, 0, 0, 0);
                a = __builtin_amdgcn_mfma_f32_16x16x32_f16(zl[t][1], bh1, a, 0, 0, 0);
                a = __builtin_amdgcn_mfma_f32_16x16x32_f16(zh[t][1], bl1, a, 0, 0, 0);
                #pragma unroll
                for (int r = 0; r < 4; ++r)
                    PT[t][f][r] = a[r] * PC[t][f][r] - b * PT[t][f][r];
            }
        }
    };

    for (int it = 0; it < NITER; ++it) {
        // load + convert z for this iter (TLP across 4 waves/SIMD + 2 blocks
        // hides the latency; transient zraw keeps us inside the 128-reg tier)
        #pragma unroll
        for (int t = 0; t < 2; ++t)
            #pragma unroll
            for (int s = 0; s < 2; ++s) {
                const float* p = z + (rowbase + (size_t)it * 32 + t * 16 + lrow) * 64
                                   + (s << 5) + (lhi << 3);
                const float4 q0 = *(const float4*)(p);
                const float4 q1 = *(const float4*)(p + 4);
                const float vv[8] = {q0.x, q0.y, q0.z, q0.w, q1.x, q1.y, q1.z, q1.w};
                #pragma unroll
                for (int j = 0; j < 8; ++j) {
                    const _Float16 h = (_Float16)vv[j];
                    zh[t][s][j] = h;
                    zl[t][s][j] = (_Float16)(vv[j] - (float)h);
                }
            }

        // Legendre chain: pA = P1, pB = P2, then ping-pong; P6 ends in pB
        f32x4 pA[2][4], pB[2][4];
        // mat 0 -> pA  (P1)
        #pragma unroll
        for (int f = 0; f < 4; ++f) {
            const int fr0 = f, fr1 = 4 + f;
            const f16x8 bh0 = *(const f16x8*)(smem + BH_OFF + fr0 * 1024 + lane * 16);
            const f16x8 bh1 = *(const f16x8*)(smem + BH_OFF + fr1 * 1024 + lane * 16);
            const f16x8 bl0 = *(const f16x8*)(wsbl + fr0 * 1024 + lane * 16);
            const f16x8 bl1 = *(const f16x8*)(wsbl + fr1 * 1024 + lane * 16);
            #pragma unroll
            for (int t = 0; t < 2; ++t) {
                f32x4 a = {0.f, 0.f, 0.f, 0.f};
                a = __builtin_amdgcn_mfma_f32_16x16x32_f16(zh[t][0], bh0, a, 0, 0, 0);
                a = __builtin_amdgcn_mfma_f32_16x16x32_f16(zl[t][0], bh0, a, 0, 0, 0);
                a = __builtin_amdgcn_mfma_f32_16x16x32_f16(zh[t][0], bl0, a, 0, 0, 0);
                a = __builtin_amdgcn_mfma_f32_16x16x32_f16(zh[t][1], bh1, a, 0, 0, 0);
                a = __builtin_amdgcn_mfma_f32_16x16x32_f16(zl[t][1], bh1, a, 0, 0, 0);
                a = __builtin_amdgcn_mfma_f32_16x16x32_f16(zh[t][1], bl1, a, 0, 0, 0);
                pA[t][f] = a;
            }
        }
        // mat 1 -> pB = W2*pA - 0.5  (P2; P0 = ones)
        #pragma unroll
        for (int f = 0; f < 4; ++f) {
            const int fr0 = 8 + f, fr1 = 12 + f;
            const f16x8 bh0 = *(const f16x8*)(smem + BH_OFF + fr0 * 1024 + lane * 16);
            const f16x8 bh1 = *(const f16x8*)(smem + BH_OFF + fr1 * 1024 + lane * 16);
            const f16x8 bl0 = *(const f16x8*)(wsbl + fr0 * 1024 + lane * 16);
            const f16x8 bl1 = *(const f16x8*)(wsbl + fr1 * 1024 + lane * 16);
            #pragma unroll
            for (int t = 0; t < 2; ++t) {
                f32x4 a = {0.f, 0.f, 0.f, 0.f};
                a = __builtin_amdgcn_mfma_f32_16x16x32_f16(zh[t][0], bh0, a, 0, 0, 0);
                a = __builtin_amdgcn_mfma_f32_16x16x32_f16(zl[t][0], bh0, a, 0, 0, 0);
                a = __builtin_amdgcn_mfma_f32_16x16x32_f16(zh[t][0], bl0, a, 0, 0, 0);
                a = __builtin_amdgcn_mfma_f32_16x16x32_f16(zh[t][1], bh1, a, 0, 0, 0);
                a = __builtin_amdgcn_mfma_f32_16x16x32_f16(zl[t][1], bh1, a, 0, 0, 0);
                a = __builtin_amdgcn_mfma_f32_16x16x32_f16(zh[t][1], bl1, a, 0, 0, 0);
                #pragma unroll
                for (int r = 0; r < 4; ++r)
                    pB[t][f][r] = a[r] * pA[t][f][r] - 0.5f;
            }
        }
        leg_step(2, 2.f / 3.f, pB, pA);   // P3
        leg_step(3, 3.f / 4.f, pA, pB);   // P4
        leg_step(4, 4.f / 5.f, pB, pA);   // P5
        leg_step(5, 5.f / 6.f, pA, pB);   // P6 = pB

        // ---------------- epilogue: out = P6 @ C^T + beta -------------------
        #pragma unroll
        for (int t = 0; t < 2; ++t) {
            // transpose P6 (C/D layout) -> A-op layout, two k-32 phases through
            // a 16x32 XOR-swizzled scratch (2 KB/wave)
            s16x8 p6h[2], p6l[2];
            #pragma unroll
            for (int s = 0; s < 2; ++s) {
                #pragma unroll
                for (int f_ = 0; f_ < 2; ++f_) {
                    const int f    = 2 * s + f_;
                    const int colp = (f_ << 4) + lrow;
                    #pragma unroll
                    for (int r = 0; r < 4; ++r) {
                        const int row = lhi * 4 + r;
                        const int g4  = ((colp >> 2) ^ row) & 7;
                        scr[row * 32 + g4 * 4 + (colp & 3)] = pB[t][f][r];
                    }
                }
                // wave-synchronous read-back (compiler inserts lgkmcnt wait)
                float vv[8];
                #pragma unroll
                for (int jg = 0; jg < 2; ++jg) {
                    const int g4r = (((lhi << 1) + jg) ^ lrow) & 7;
                    const float4 q = *(const float4*)(scr + lrow * 32 + g4r * 4);
                    vv[jg * 4 + 0] = q.x; vv[jg * 4 + 1] = q.y;
                    vv[jg * 4 + 2] = q.z; vv[jg * 4 + 3] = q.w;
                }
                #pragma unroll
                for (int j = 0; j < 8; ++j) {
                    const unsigned short h = f2bf(vv[j]);
                    const float hf = __builtin_bit_cast(float, (unsigned)h << 16);
                    p6h[s][j] = (short)h;
                    p6l[s][j] = (short)f2bf(vv[j] - hf);
                }
            }
            // C-frags loaded per-fo so they stay transient
            #pragma unroll
            for (int fo = 0; fo < 2; ++fo) {
                const s16x8 ch0 = *(const s16x8*)(smem + CF_OFF + ((0 << 1) + fo) * 1024 + lane * 16);
                const s16x8 ch1 = *(const s16x8*)(smem + CF_OFF + ((1 << 1) + fo) * 1024 + lane * 16);
                const s16x8 cl0 = *(const s16x8*)(smem + CF_OFF + ((2 << 1) + fo) * 1024 + lane * 16);
                const s16x8 cl1 = *(const s16x8*)(smem + CF_OFF + ((3 << 1) + fo) * 1024 + lane * 16);
                f32x4 o = {0.f, 0.f, 0.f, 0.f};
                o = __builtin_amdgcn_mfma_f32_16x16x32_bf16(p6h[0], ch0, o, 0, 0, 0);
                o = __builtin_amdgcn_mfma_f32_16x16x32_bf16(p6l[0], ch0, o, 0, 0, 0);
                o = __builtin_amdgcn_mfma_f32_16x16x32_bf16(p6h[0], cl0, o, 0, 0, 0);
                o = __builtin_amdgcn_mfma_f32_16x16x32_bf16(p6h[1], ch1, o, 0, 0, 0);
                o = __builtin_amdgcn_mfma_f32_16x16x32_bf16(p6l[1], ch1, o, 0, 0, 0);
                o = __builtin_amdgcn_mfma_f32_16x16x32_bf16(p6h[1], cl1, o, 0, 0, 0);
                const float bb = fo ? beta1 : beta0;
                const size_t r0 = rowbase + (size_t)it * 32 + t * 16 + lhi * 4;
                #pragma unroll
                for (int r = 0; r < 4; ++r)
                    out[(r0 + r) * 32 + (fo << 4) + lrow] = o[r] + bb;
            }
        }
    }
}

extern "C" void kernel_launch(void* const* d_in, const int* in_sizes, int n_in,
                              void* d_out, int out_size, void* d_ws, size_t ws_size,
                              hipStream_t stream) {
    const float* z    = (const float*)d_in[0];
    const float* T    = (const float*)d_in[1];
    const float* C    = (const float*)d_in[2];
    const float* beta = (const float*)d_in[3];
    float* out = (float*)d_out;
    (void)in_sizes; (void)n_in; (void)out_size; (void)ws_size;

    char* ws = (char*)d_ws;              // needs WS_TOTAL = 104 KB

    leg_prep<<<1, 512, 0, stream>>>(T, C, ws);

    hipFuncSetAttribute((const void*)leg_mfma,
                        hipFuncAttributeMaxDynamicSharedMemorySize, SMEM_BYTES);
    leg_mfma<<<BLOCKS, THREADS, SMEM_BYTES, stream>>>(z, ws, beta, out);
}

// Round 7
// 105.077 us; speedup vs baseline: 1.3949x; 1.3949x over previous
//
#include <hip/hip_runtime.h>

// Legendre2 via split-precision MFMA, v7: time-multiplexed A-table.
// Prep kernel materializes f16 hi/lo fragment tables of A (=coef*Tnorm) and
// bf16 hi/lo fragment table of C into d_ws in final MFMA lane layout.
// Main kernel: 2048 blocks x 512 thr; LDS holds 3 mats' hi+lo frags (48 KB)
// + C (8 KB) + scratch (16 KB) = 72 KB -> 2 blocks/CU = 4 waves/SIMD.
// The Legendre chain uses mats 0-2 then 3-5, so the A region is restaged
// mid-kernel (barrier + 48 KB copy, hidden by the sibling block).
// Inner loop reads operands ONLY from LDS (v6 lesson: global-latency loads
// in the MFMA chain blow the 128-reg budget and spill).
// W_i = Z @ A_i^T as f16 hi/lo 3-term MFMA (f32 accum), elementwise Legendre
// fold in f32 regs, epilogue P6 @ C^T + beta as bf16 hi/lo 3-term MFMA.
// N=524288, D=64, K=64, O=32, DEGREE=6.

typedef _Float16 f16x8 __attribute__((ext_vector_type(8)));
typedef short    s16x8 __attribute__((ext_vector_type(8)));
typedef float    f32x4 __attribute__((ext_vector_type(4)));

#define NN      524288
#define BLOCKS  2048
#define THREADS 512
#define NWAVES  8
// each wave owns one 32-row tile: 2048 blocks * 8 waves * 32 rows = N

// d_ws byte layout (prep kernel output)
#define WS_BH   0                       // 48 frags * 1 KB  (f16 hi of A)
#define WS_CF   49152                   // 8 frags * 1 KB   (bf16 h/l of C)
#define WS_BL   57344                   // 48 frags * 1 KB  (f16 lo of A)
#define WS_TOTAL 106496

// main-kernel LDS byte offsets
#define AH_OFF  0                       // 3 mats * 8 frags * 1 KB = 24 KB
#define AL_OFF  24576                   // 24 KB
#define CF_OFF  49152                   // 8 KB
#define SCR_OFF 57344                   // 8 waves * 2 KB transpose scratch
#define SMEM_BYTES (SCR_OFF + NWAVES * 2048)   // 73728 B -> 2 blocks/CU

__device__ __forceinline__ unsigned short f2bf(float x) {
    unsigned u = __builtin_bit_cast(unsigned, x);
    return (unsigned short)((u + 0x7FFFu + ((u >> 16) & 1u)) >> 16);
}

// ---------------------------------------------------------------------------
// prep: build fragment tables in d_ws (runs every launch; ~100 KB of work)
// ---------------------------------------------------------------------------
__global__ __launch_bounds__(512) void leg_prep(
    const float* __restrict__ T, const float* __restrict__ Cm,
    char* __restrict__ ws)
{
    __shared__ float scale_s[384];
    const int tid = (int)threadIdx.x;

    if (tid < 384) {
        const int mat = tid >> 6, kc = tid & 63;
        const float4* tr = (const float4*)(T + (size_t)((mat << 6) + kc) * 64);
        float s = 0.f;
        #pragma unroll
        for (int q = 0; q < 16; ++q) { float4 v = tr[q]; s += v.x + v.y + v.z + v.w; }
        float sc;
        if (mat == 0) sc = 1.f;
        else { const float fi = (float)(mat + 1); sc = (2.f * fi - 1.f) / fi / s; }
        scale_s[tid] = sc;
    }
    __syncthreads();

    // A fragments: frag(mat,s,f), lane l supplies A[col][32s+(l>>4)*8+j]*scale
    // with col=(l&15)+16f.
    for (int g = tid; g < 3072; g += 512) {
        const int mat = g >> 9;
        const int s   = (g >> 8) & 1;
        const int f   = (g >> 6) & 3;
        const int l   = g & 63;
        const int kc  = (l & 15) + (f << 4);
        const int d0  = ((l >> 4) << 3) + (s << 5);
        const float sc = scale_s[(mat << 6) + kc];
        const float* src = T + (size_t)((mat << 6) + kc) * 64 + d0;
        const float4 v0 = *(const float4*)(src);
        const float4 v1 = *(const float4*)(src + 4);
        const float vv[8] = {v0.x, v0.y, v0.z, v0.w, v1.x, v1.y, v1.z, v1.w};
        f16x8 hi, lo;
        #pragma unroll
        for (int j = 0; j < 8; ++j) {
            const float x = vv[j] * sc;
            const _Float16 h = (_Float16)x;
            hi[j] = h;
            lo[j] = (_Float16)(x - (float)h);
        }
        const int fr = (((mat << 1) + s) << 2) + f;
        *(f16x8*)(ws + WS_BH + fr * 1024 + l * 16) = hi;
        *(f16x8*)(ws + WS_BL + fr * 1024 + l * 16) = lo;
    }

    // C fragments (bf16 hi/lo): frag(hl,s,fo), lane l supplies
    // C2[k=32s+(l>>4)*8+j][o=(l&15)+16fo] = C[o][k].
    {
        const int hl = (tid >> 8) & 1;
        const int s  = (tid >> 7) & 1;
        const int fo = (tid >> 6) & 1;
        const int l  = tid & 63;
        const int o  = (l & 15) + (fo << 4);
        const int k0 = ((l >> 4) << 3) + (s << 5);
        const float* src = Cm + (size_t)o * 64 + k0;
        const float4 v0 = *(const float4*)src;
        const float4 v1 = *(const float4*)(src + 4);
        const float vv[8] = {v0.x, v0.y, v0.z, v0.w, v1.x, v1.y, v1.z, v1.w};
        s16x8 fr;
        #pragma unroll
        for (int j = 0; j < 8; ++j) {
            const float x = vv[j];
            const unsigned short h = f2bf(x);
            if (hl) {
                const float hf = __builtin_bit_cast(float, (unsigned)h << 16);
                fr[j] = (short)f2bf(x - hf);
            } else {
                fr[j] = (short)h;
            }
        }
        *(s16x8*)(ws + WS_CF + ((((hl << 1) + s) << 1) + fo) * 1024 + l * 16) = fr;
    }
}

// ---------------------------------------------------------------------------
// main
// ---------------------------------------------------------------------------
__global__ __launch_bounds__(THREADS) void leg_mfma(
    const float* __restrict__ z, const char* __restrict__ ws,
    const float* __restrict__ beta, float* __restrict__ out)
{
    extern __shared__ char smem[];
    const int tid  = (int)threadIdx.x;
    const int lane = tid & 63;
    const int wv   = tid >> 6;
    const int lrow = lane & 15;          // row (A-op) / col (C/D) index
    const int lhi  = lane >> 4;          // 0..3

    // stage A mats [3*stage, 3*stage+3): 48 KB hi+lo
    auto stage_A = [&](int stage) {
        const char* srcH = ws + WS_BH + stage * 24576;
        const char* srcL = ws + WS_BL + stage * 24576;
        for (int i = tid; i < 1536; i += THREADS) {
            *(f16x8*)(smem + AH_OFF + i * 16) = *(const f16x8*)(srcH + i * 16);
            *(f16x8*)(smem + AL_OFF + i * 16) = *(const f16x8*)(srcL + i * 16);
        }
    };

    // initial stage: mats 0-2 + C frags
    stage_A(0);
    for (int i = tid; i < 512; i += THREADS)
        *(f16x8*)(smem + CF_OFF + i * 16) = *(const f16x8*)(ws + WS_CF + i * 16);

    const int    gw      = blockIdx.x * NWAVES + wv;
    const size_t rowbase = (size_t)gw * 32;
    float* scr = (float*)(smem + SCR_OFF) + wv * 512;   // 16 rows x 32 f32

    const float beta0 = beta[lrow];
    const float beta1 = beta[16 + lrow];

    // load z (issued before the staging barrier so HBM latency overlaps it)
    float4 zraw[2][4];
    #pragma unroll
    for (int t = 0; t < 2; ++t)
        #pragma unroll
        for (int s = 0; s < 2; ++s) {
            const float* p = z + (rowbase + t * 16 + lrow) * 64 + (s << 5) + (lhi << 3);
            zraw[t][2 * s]     = *(const float4*)(p);
            zraw[t][2 * s + 1] = *(const float4*)(p + 4);
        }
    __syncthreads();

    // convert z to f16 hi/lo fragments
    f16x8 zh[2][2], zl[2][2];
    #pragma unroll
    for (int t = 0; t < 2; ++t)
        #pragma unroll
        for (int s = 0; s < 2; ++s) {
            const float4 q0 = zraw[t][2 * s], q1 = zraw[t][2 * s + 1];
            const float vv[8] = {q0.x, q0.y, q0.z, q0.w, q1.x, q1.y, q1.z, q1.w};
            #pragma unroll
            for (int j = 0; j < 8; ++j) {
                const _Float16 h = (_Float16)vv[j];
                zh[t][s][j] = h;
                zl[t][s][j] = (_Float16)(vv[j] - (float)h);
            }
        }

    // one Legendre level from LDS frags of local mat lm (0..2 within stage):
    // PT := W * PC - b * PT
    auto leg_step = [&](int lm, float b, f32x4 (&PC)[2][4], f32x4 (&PT)[2][4]) {
        #pragma unroll
        for (int f = 0; f < 4; ++f) {
            const int fr0 = lm * 8 + f;        // s=0
            const int fr1 = lm * 8 + 4 + f;    // s=1
            const f16x8 bh0 = *(const f16x8*)(smem + AH_OFF + fr0 * 1024 + lane * 16);
            const f16x8 bl0 = *(const f16x8*)(smem + AL_OFF + fr0 * 1024 + lane * 16);
            const f16x8 bh1 = *(const f16x8*)(smem + AH_OFF + fr1 * 1024 + lane * 16);
            const f16x8 bl1 = *(const f16x8*)(smem + AL_OFF + fr1 * 1024 + lane * 16);
            #pragma unroll
            for (int t = 0; t < 2; ++t) {
                f32x4 a = {0.f, 0.f, 0.f, 0.f};
                a = __builtin_amdgcn_mfma_f32_16x16x32_f16(zh[t][0], bh0, a, 0, 0, 0);
                a = __builtin_amdgcn_mfma_f32_16x16x32_f16(zl[t][0], bh0, a, 0, 0, 0);
                a = __builtin_amdgcn_mfma_f32_16x16x32_f16(zh[t][0], bl0, a, 0, 0, 0);
                a = __builtin_amdgcn_mfma_f32_16x16x32_f16(zh[t][1], bh1, a, 0, 0, 0);
                a = __builtin_amdgcn_mfma_f32_16x16x32_f16(zl[t][1], bh1, a, 0, 0, 0);
                a = __builtin_amdgcn_mfma_f32_16x16x32_f16(zh[t][1], bl1, a, 0, 0, 0);
                #pragma unroll
                for (int r = 0; r < 4; ++r)
                    PT[t][f][r] = a[r] * PC[t][f][r] - b * PT[t][f][r];
            }
        }
    };

    // ---------------- stage 0: mats 0,1,2 -> P1, P2, P3 ----------------------
    f32x4 pA[2][4], pB[2][4];
    // mat 0 -> pA  (P1)
    #pragma unroll
    for (int f = 0; f < 4; ++f) {
        const int fr0 = f, fr1 = 4 + f;
        const f16x8 bh0 = *(const f16x8*)(smem + AH_OFF + fr0 * 1024 + lane * 16);
        const f16x8 bl0 = *(const f16x8*)(smem + AL_OFF + fr0 * 1024 + lane * 16);
        const f16x8 bh1 = *(const f16x8*)(smem + AH_OFF + fr1 * 1024 + lane * 16);
        const f16x8 bl1 = *(const f16x8*)(smem + AL_OFF + fr1 * 1024 + lane * 16);
        #pragma unroll
        for (int t = 0; t < 2; ++t) {
            f32x4 a = {0.f, 0.f, 0.f, 0.f};
            a = __builtin_amdgcn_mfma_f32_16x16x32_f16(zh[t][0], bh0, a, 0, 0, 0);
            a = __builtin_amdgcn_mfma_f32_16x16x32_f16(zl[t][0], bh0, a, 0, 0, 0);
            a = __builtin_amdgcn_mfma_f32_16x16x32_f16(zh[t][0], bl0, a, 0, 0, 0);
            a = __builtin_amdgcn_mfma_f32_16x16x32_f16(zh[t][1], bh1, a, 0, 0, 0);
            a = __builtin_amdgcn_mfma_f32_16x16x32_f16(zl[t][1], bh1, a, 0, 0, 0);
            a = __builtin_amdgcn_mfma_f32_16x16x32_f16(zh[t][1], bl1, a, 0, 0, 0);
            pA[t][f] = a;
        }
    }
    // mat 1 -> pB = W2*pA - 0.5  (P2; P0 = ones)
    #pragma unroll
    for (int f = 0; f < 4; ++f) {
        const int fr0 = 8 + f, fr1 = 12 + f;
        const f16x8 bh0 = *(const f16x8*)(smem + AH_OFF + fr0 * 1024 + lane * 16);
        const f16x8 bl0 = *(const f16x8*)(smem + AL_OFF + fr0 * 1024 + lane * 16);
        const f16x8 bh1 = *(const f16x8*)(smem + AH_OFF + fr1 * 1024 + lane * 16);
        const f16x8 bl1 = *(const f16x8*)(smem + AL_OFF + fr1 * 1024 + lane * 16);
        #pragma unroll
        for (int t = 0; t < 2; ++t) {
            f32x4 a = {0.f, 0.f, 0.f, 0.f};
            a = __builtin_amdgcn_mfma_f32_16x16x32_f16(zh[t][0], bh0, a, 0, 0, 0);
            a = __builtin_amdgcn_mfma_f32_16x16x32_f16(zl[t][0], bh0, a, 0, 0, 0);
            a = __builtin_amdgcn_mfma_f32_16x16x32_f16(zh[t][0], bl0, a, 0, 0, 0);
            a = __builtin_amdgcn_mfma_f32_16x16x32_f16(zh[t][1], bh1, a, 0, 0, 0);
            a = __builtin_amdgcn_mfma_f32_16x16x32_f16(zl[t][1], bh1, a, 0, 0, 0);
            a = __builtin_amdgcn_mfma_f32_16x16x32_f16(zh[t][1], bl1, a, 0, 0, 0);
            #pragma unroll
            for (int r = 0; r < 4; ++r)
                pB[t][f][r] = a[r] * pA[t][f][r] - 0.5f;
        }
    }
    leg_step(2, 2.f / 3.f, pB, pA);       // P3 -> pA

    // ---------------- restage: mats 3,4,5 ------------------------------------
    __syncthreads();                      // all waves done with mats 0-2
    stage_A(1);
    __syncthreads();                      // table ready

    leg_step(0, 3.f / 4.f, pA, pB);       // P4 -> pB   (local mat 0 = mat 3)
    leg_step(1, 4.f / 5.f, pB, pA);       // P5 -> pA
    leg_step(2, 5.f / 6.f, pA, pB);       // P6 -> pB

    // ---------------- epilogue: out = P6 @ C^T + beta ------------------------
    #pragma unroll
    for (int t = 0; t < 2; ++t) {
        // transpose P6 (C/D layout) -> A-op layout, two k-32 phases through
        // a 16x32 XOR-swizzled scratch (2 KB/wave)
        s16x8 p6h[2], p6l[2];
        #pragma unroll
        for (int s = 0; s < 2; ++s) {
            #pragma unroll
            for (int f_ = 0; f_ < 2; ++f_) {
                const int f    = 2 * s + f_;
                const int colp = (f_ << 4) + lrow;
                #pragma unroll
                for (int r = 0; r < 4; ++r) {
                    const int row = lhi * 4 + r;
                    const int g4  = ((colp >> 2) ^ row) & 7;
                    scr[row * 32 + g4 * 4 + (colp & 3)] = pB[t][f][r];
                }
            }
            // wave-synchronous read-back (compiler inserts lgkmcnt wait)
            float vv[8];
            #pragma unroll
            for (int jg = 0; jg < 2; ++jg) {
                const int g4r = (((lhi << 1) + jg) ^ lrow) & 7;
                const float4 q = *(const float4*)(scr + lrow * 32 + g4r * 4);
                vv[jg * 4 + 0] = q.x; vv[jg * 4 + 1] = q.y;
                vv[jg * 4 + 2] = q.z; vv[jg * 4 + 3] = q.w;
            }
            #pragma unroll
            for (int j = 0; j < 8; ++j) {
                const unsigned short h = f2bf(vv[j]);
                const float hf = __builtin_bit_cast(float, (unsigned)h << 16);
                p6h[s][j] = (short)h;
                p6l[s][j] = (short)f2bf(vv[j] - hf);
            }
        }
        // C-frags loaded per-fo so they stay transient
        #pragma unroll
        for (int fo = 0; fo < 2; ++fo) {
            const s16x8 ch0 = *(const s16x8*)(smem + CF_OFF + ((0 << 1) + fo) * 1024 + lane * 16);
            const s16x8 ch1 = *(const s16x8*)(smem + CF_OFF + ((1 << 1) + fo) * 1024 + lane * 16);
            const s16x8 cl0 = *(const s16x8*)(smem + CF_OFF + ((2 << 1) + fo) * 1024 + lane * 16);
            const s16x8 cl1 = *(const s16x8*)(smem + CF_OFF + ((3 << 1) + fo) * 1024 + lane * 16);
            f32x4 o = {0.f, 0.f, 0.f, 0.f};
            o = __builtin_amdgcn_mfma_f32_16x16x32_bf16(p6h[0], ch0, o, 0, 0, 0);
            o = __builtin_amdgcn_mfma_f32_16x16x32_bf16(p6l[0], ch0, o, 0, 0, 0);
            o = __builtin_amdgcn_mfma_f32_16x16x32_bf16(p6h[0], cl0, o, 0, 0, 0);
            o = __builtin_amdgcn_mfma_f32_16x16x32_bf16(p6h[1], ch1, o, 0, 0, 0);
            o = __builtin_amdgcn_mfma_f32_16x16x32_bf16(p6l[1], ch1, o, 0, 0, 0);
            o = __builtin_amdgcn_mfma_f32_16x16x32_bf16(p6h[1], cl1, o, 0, 0, 0);
            const float bb = fo ? beta1 : beta0;
            const size_t r0 = rowbase + t * 16 + lhi * 4;
            #pragma unroll
            for (int r = 0; r < 4; ++r)
                out[(r0 + r) * 32 + (fo << 4) + lrow] = o[r] + bb;
        }
    }
}

extern "C" void kernel_launch(void* const* d_in, const int* in_sizes, int n_in,
                              void* d_out, int out_size, void* d_ws, size_t ws_size,
                              hipStream_t stream) {
    const float* z    = (const float*)d_in[0];
    const float* T    = (const float*)d_in[1];
    const float* C    = (const float*)d_in[2];
    const float* beta = (const float*)d_in[3];
    float* out = (float*)d_out;
    (void)in_sizes; (void)n_in; (void)out_size; (void)ws_size;

    char* ws = (char*)d_ws;              // needs WS_TOTAL = 104 KB

    leg_prep<<<1, 512, 0, stream>>>(T, C, ws);

    hipFuncSetAttribute((const void*)leg_mfma,
                        hipFuncAttributeMaxDynamicSharedMemorySize, SMEM_BYTES);
    leg_mfma<<<BLOCKS, THREADS, SMEM_BYTES, stream>>>(z, ws, beta, out);
}